// Round 9
// baseline (147.638 us; speedup 1.0000x reference)
//
#include <hip/hip_runtime.h>
#include <math.h>

#define IN_C 512
#define HID  64
#define OUTC 40

typedef __attribute__((ext_vector_type(8))) short bf16x8;
typedef __attribute__((ext_vector_type(4))) short bf16x4;
typedef __attribute__((ext_vector_type(4))) float f32x4;

#define GDEPTH 12

__device__ __forceinline__ ushort f2bf(float f) {          // RNE
    uint u = __float_as_uint(f);
    u += 0x7FFFu + ((u >> 16) & 1u);
    return (ushort)(u >> 16);
}
__device__ __forceinline__ float bf2f(ushort s) {
    return __uint_as_float(((uint)s) << 16);
}

// ---------------- zero cnt (replaces pathologically slow rocclr fill) ----------------
__global__ void k_zero(int4* __restrict__ p, int n4) {
    int i = blockIdx.x * blockDim.x + threadIdx.x;
    if (i < n4) p[i] = make_int4(0, 0, 0, 0);
}

// ---------------- histogram of dst + per-edge rank (+ W1 split folded in) ----------------
__global__ void k_histsplit(const int* __restrict__ dst, int E,
                            int* __restrict__ cnt, int* __restrict__ rank,
                            int nbE2,
                            const float* __restrict__ W,
                            ushort* __restrict__ hi, ushort* __restrict__ lo) {
    if (blockIdx.x < (unsigned)nbE2) {
        int i = (blockIdx.x * blockDim.x + threadIdx.x) * 2;
        if (i < E) {
            if (i + 1 < E) {
                int2 d = *(const int2*)&dst[i];
                int r0 = atomicAdd(&cnt[d.x], 1);
                int r1 = atomicAdd(&cnt[d.y], 1);
                *(int2*)&rank[i] = make_int2(r0, r1);
            } else {
                rank[i] = atomicAdd(&cnt[dst[i]], 1);
            }
        }
    } else {
        // W1 split to hi/lo bf16, transposed: WT[c][k]
        int i = (blockIdx.x - nbE2) * blockDim.x + threadIdx.x;   // over 64*512
        if (i >= HID * IN_C) return;
        int c = i >> 9, k = i & 511;
        float v = W[(size_t)k * HID + c];
        uint ub = __float_as_uint(v);
        uint hb = ub & 0xFFFF0000u;
        float lf = v - __uint_as_float(hb);
        hi[i] = (ushort)(ub >> 16);
        lo[i] = (ushort)(__float_as_uint(lf) >> 16);
    }
}

// ---------------- prefix scan ----------------
__global__ void k_scan1(const int* __restrict__ cnt, int N,
                        int* __restrict__ rowptr, int* __restrict__ bsum) {
    __shared__ int s[256];
    int t = threadIdx.x;
    int i = blockIdx.x * 256 + t;
    int v = (i < N) ? cnt[i] : 0;
    int x = v;
    s[t] = x; __syncthreads();
    #pragma unroll
    for (int o = 1; o < 256; o <<= 1) {
        int y = (t >= o) ? s[t - o] : 0;
        __syncthreads();
        x += y; s[t] = x;
        __syncthreads();
    }
    if (i < N) rowptr[i] = x - v;          // exclusive
    if (t == 255) bsum[blockIdx.x] = x;    // block total
}

// scan2+scan3 fused: every block redundantly scans bsum (nb<=256), then
// applies its own block prefix + writes dinv.
__global__ void k_scan23(int* __restrict__ rowptr, const int* __restrict__ bsum,
                         const int* __restrict__ cnt, float* __restrict__ dinv,
                         int N, int E, int nb) {
    __shared__ int s[256];
    int t = threadIdx.x;
    int v = (t < nb) ? bsum[t] : 0;
    int x = v;
    s[t] = x; __syncthreads();
    #pragma unroll
    for (int o = 1; o < 256; o <<= 1) {
        int y = (t >= o) ? s[t - o] : 0;
        __syncthreads();
        x += y; s[t] = x;
        __syncthreads();
    }
    int bpre = (blockIdx.x > 0) ? s[blockIdx.x - 1] : 0;
    int i = blockIdx.x * 256 + t;
    if (i < N) {
        rowptr[i] += bpre;
        dinv[i] = rsqrtf(1.0f + (float)cnt[i]);   // self-loop => deg >= 1
        if (i == 0) rowptr[N] = E;
    }
}

// ---------------- counting-sort scatter (atomic-free) ----------------
__global__ void k_fill(const int* __restrict__ src, const int* __restrict__ dst,
                       const int* __restrict__ rank, int E,
                       const int* __restrict__ rowptr, int* __restrict__ ssort) {
    int i = (blockIdx.x * blockDim.x + threadIdx.x) * 2;
    if (i >= E) return;
    if (i + 1 < E) {
        int2 d = *(const int2*)&dst[i];
        int2 s = *(const int2*)&src[i];
        int2 r = *(const int2*)&rank[i];
        int p0 = rowptr[d.x] + r.x;
        int p1 = rowptr[d.y] + r.y;
        ssort[p0] = s.x;
        ssort[p1] = s.y;
    } else {
        ssort[rowptr[dst[i]] + rank[i]] = src[i];
    }
}

// ---------------- GEMM1: LDS-staged split-bf16 MFMA, bf16 output ----------------
__global__ __launch_bounds__(256) void k_gemm1(const float* __restrict__ x,
                                               const ushort* __restrict__ WThi,
                                               const ushort* __restrict__ WTlo,
                                               const float* __restrict__ dinv,
                                               ushort* __restrict__ h1s, int N) {
    __shared__ ushort Ah[2][64 * 40], Al[2][64 * 40];
    __shared__ ushort Bh[2][64 * 40], Bl[2][64 * 40];
    int t = threadIdx.x;
    int wid = t >> 6, lane = t & 63;
    int lr = lane & 15, lko = lane >> 4;
    int wm = wid >> 1, wn = wid & 1;
    int row0 = blockIdx.x * 64;

    int srow = t >> 3, sf4 = t & 7;
    int scol = t >> 2, sseg = t & 3;
    int xr0 = row0 + srow;      if (xr0 >= N) xr0 = N - 1;
    int xr1 = row0 + srow + 32; if (xr1 >= N) xr1 = N - 1;
    const float* xp0 = x + (size_t)xr0 * IN_C + sf4 * 4;
    const float* xp1 = x + (size_t)xr1 * IN_C + sf4 * 4;
    const ushort* bhp = WThi + (size_t)scol * IN_C + sseg * 8;
    const ushort* blp = WTlo + (size_t)scol * IN_C + sseg * 8;

    f32x4 acc[2][2] = {};
    float4 xrg[2];
    bf16x8 bhr, blr;

    auto stage_load = [&](int kt) {
        xrg[0] = *(const float4*)(xp0 + kt);
        xrg[1] = *(const float4*)(xp1 + kt);
        bhr = *(const bf16x8*)(bhp + kt);
        blr = *(const bf16x8*)(blp + kt);
    };
    auto stage_write = [&](int b) {
        #pragma unroll
        for (int p = 0; p < 2; ++p) {
            float xv[4];
            *(float4*)xv = xrg[p];
            bf16x4 h, l;
            #pragma unroll
            for (int j = 0; j < 4; ++j) {
                uint ub = __float_as_uint(xv[j]);
                float hf = __uint_as_float(ub & 0xFFFF0000u);
                float lf = xv[j] - hf;
                h[j] = (short)(ub >> 16);
                l[j] = (short)(__float_as_uint(lf) >> 16);
            }
            int row = srow + p * 32;
            *(bf16x4*)&Ah[b][row * 40 + sf4 * 4] = h;
            *(bf16x4*)&Al[b][row * 40 + sf4 * 4] = l;
        }
        *(bf16x8*)&Bh[b][scol * 40 + sseg * 8] = bhr;
        *(bf16x8*)&Bl[b][scol * 40 + sseg * 8] = blr;
    };
    auto compute = [&](int b) {
        bf16x8 afh[2], afl[2], bfh[2], bfl[2];
        #pragma unroll
        for (int mf = 0; mf < 2; ++mf) {
            int row = wm * 32 + mf * 16 + lr;
            afh[mf] = *(const bf16x8*)&Ah[b][row * 40 + lko * 8];
            afl[mf] = *(const bf16x8*)&Al[b][row * 40 + lko * 8];
        }
        #pragma unroll
        for (int nf = 0; nf < 2; ++nf) {
            int col = wn * 32 + nf * 16 + lr;
            bfh[nf] = *(const bf16x8*)&Bh[b][col * 40 + lko * 8];
            bfl[nf] = *(const bf16x8*)&Bl[b][col * 40 + lko * 8];
        }
        #pragma unroll
        for (int mf = 0; mf < 2; ++mf)
            #pragma unroll
            for (int nf = 0; nf < 2; ++nf) {
                acc[mf][nf] = __builtin_amdgcn_mfma_f32_16x16x32_bf16(afh[mf], bfh[nf], acc[mf][nf], 0, 0, 0);
                acc[mf][nf] = __builtin_amdgcn_mfma_f32_16x16x32_bf16(afl[mf], bfh[nf], acc[mf][nf], 0, 0, 0);
                acc[mf][nf] = __builtin_amdgcn_mfma_f32_16x16x32_bf16(afh[mf], bfl[nf], acc[mf][nf], 0, 0, 0);
            }
    };

    stage_load(0);
    stage_write(0);
    __syncthreads();

    #pragma unroll
    for (int i = 0; i < 16; ++i) {
        if (i < 15) stage_load((i + 1) * 32);
        compute(i & 1);
        if (i < 15) stage_write((i + 1) & 1);
        __syncthreads();
    }

    #pragma unroll
    for (int mf = 0; mf < 2; ++mf)
        #pragma unroll
        for (int r = 0; r < 4; ++r) {
            int orow = row0 + wm * 32 + mf * 16 + lko * 4 + r;
            if (orow < N) {
                float dv = dinv[orow];
                #pragma unroll
                for (int nf = 0; nf < 2; ++nf)
                    h1s[(size_t)orow * HID + wn * 32 + nf * 16 + lr] = f2bf(dv * acc[mf][nf][r]);
            }
        }
}

// ---------------- fused agg1 + gemm2 (bf16 h1s gather, bf16 h2s out) ----------------
__global__ __launch_bounds__(256) void k_agg1g2(const ushort* __restrict__ h1s,
                                                const int* __restrict__ rowptr,
                                                const int* __restrict__ ssort,
                                                const float* __restrict__ dinv,
                                                const float* __restrict__ b1,
                                                const float* __restrict__ W2,
                                                ushort* __restrict__ h2s, int N) {
    __shared__ float wl[HID * OUTC];      // 2560 floats = 10.24 KB
    int t = threadIdx.x;
    #pragma unroll
    for (int q0 = 0; q0 < 3; ++q0) {
        int q = t + q0 * 256;
        if (q < 640) *(float4*)&wl[q * 4] = *(const float4*)&W2[q * 4];
    }
    __syncthreads();

    int lane = t & 63;
    int wq = t >> 6;
    int lc = lane < OUTC ? lane : 0;
    float bias = b1[lane];
    int nq = (N + 3) >> 2;

    for (int q = blockIdx.x; q < nq; q += gridDim.x) {
        int node = q * 4 + wq;
        if (node >= N) continue;
        float s0 = bf2f(h1s[(size_t)node * HID + lane]);   // self-loop term
        float sv[GDEPTH];
        #pragma unroll
        for (int k = 0; k < GDEPTH; ++k) sv[k] = 0.f;
        int eu = __builtin_amdgcn_readfirstlane(rowptr[node]);
        int endu = __builtin_amdgcn_readfirstlane(rowptr[node + 1]);
        for (int e = eu; e < endu; e += GDEPTH) {
            int raw[GDEPTH];
            #pragma unroll
            for (int k = 0; k < GDEPTH; ++k) raw[k] = ssort[e + k];  // scalar s_load path
            #pragma unroll
            for (int k = 0; k < GDEPTH; ++k) {
                int ix = (e + k < endu) ? raw[k] : raw[0];
                float v = bf2f(h1s[(size_t)ix * HID + lane]);
                sv[k] += (e + k < endu) ? v : 0.f;
            }
        }
        float s = s0;
        #pragma unroll
        for (int k = 0; k < GDEPTH; ++k) s += sv[k];
        float dv = dinv[node];
        float a = fmaxf(fmaf(dv, s, bias), 0.0f);
        // in-wave gemm2: h2[c] = sum_k a[k] * W2[k][c]
        float acc = 0.f;
        #pragma unroll
        for (int k = 0; k < HID; ++k) {
            float ak = __uint_as_float(__builtin_amdgcn_readlane(__float_as_uint(a), k));
            acc = fmaf(ak, wl[k * OUTC + lc], acc);
        }
        if (lane < OUTC) h2s[(size_t)node * OUTC + lane] = f2bf(dv * acc);
    }
}

// ---------------- agg2 + bias + softmax (bf16 h2s gather) ----------------
__global__ __launch_bounds__(256) void k_agg2(const ushort* __restrict__ h2s,
                                              const int* __restrict__ rowptr,
                                              const int* __restrict__ ssort,
                                              const float* __restrict__ dinv,
                                              const float* __restrict__ b2,
                                              float* __restrict__ out, int N) {
    int lane = threadIdx.x & 63;
    int node = blockIdx.x * 4 + (threadIdx.x >> 6);
    if (node >= N) return;
    bool act = lane < OUTC;
    int lc = act ? lane : 0;
    float s0 = bf2f(h2s[(size_t)node * OUTC + lc]);
    float sv[GDEPTH];
    #pragma unroll
    for (int k = 0; k < GDEPTH; ++k) sv[k] = 0.f;
    int eu = __builtin_amdgcn_readfirstlane(rowptr[node]);
    int endu = __builtin_amdgcn_readfirstlane(rowptr[node + 1]);
    for (int e = eu; e < endu; e += GDEPTH) {
        int raw[GDEPTH];
        #pragma unroll
        for (int k = 0; k < GDEPTH; ++k) raw[k] = ssort[e + k];
        #pragma unroll
        for (int k = 0; k < GDEPTH; ++k) {
            int ix = (e + k < endu) ? raw[k] : raw[0];
            float v = bf2f(h2s[(size_t)ix * OUTC + lc]);
            sv[k] += (e + k < endu) ? v : 0.f;
        }
    }
    float s = s0;
    #pragma unroll
    for (int k = 0; k < GDEPTH; ++k) s += sv[k];
    float v = act ? (dinv[node] * s + b2[lane]) : -INFINITY;
    float m = v;
    #pragma unroll
    for (int o = 32; o; o >>= 1) m = fmaxf(m, __shfl_xor(m, o));
    float p = act ? expf(v - m) : 0.0f;
    float su = p;
    #pragma unroll
    for (int o = 32; o; o >>= 1) su += __shfl_xor(su, o);
    if (act) out[(size_t)node * OUTC + lane] = p / su;
}

static inline size_t alignup(size_t v) { return (v + 255) & ~(size_t)255; }

extern "C" void kernel_launch(void* const* d_in, const int* in_sizes, int n_in,
                              void* d_out, int out_size, void* d_ws, size_t ws_size,
                              hipStream_t stream) {
    const float* x  = (const float*)d_in[0];
    const int*   ei = (const int*)d_in[1];
    const float* W1 = (const float*)d_in[2];
    const float* b1 = (const float*)d_in[3];
    const float* W2 = (const float*)d_in[4];
    const float* b2 = (const float*)d_in[5];

    const int N = in_sizes[0] / IN_C;
    const int E = in_sizes[1] / 2;
    const int* src = ei;
    const int* dst = ei + E;

    char* w = (char*)d_ws;
    int* cnt    = (int*)w;   w += alignup((size_t)N * 4);
    int* rank   = (int*)w;   w += alignup((size_t)E * 4 + 256);
    int* rowptr = (int*)w;   w += alignup((size_t)(N + 1) * 4);
    int* bsum   = (int*)w;   w += alignup(256 * 4);
    int* ssort  = (int*)w;   w += alignup((size_t)E * 4 + 256);  // +pad: scalar tail overreads
    float* dinv = (float*)w; w += alignup((size_t)N * 4);
    ushort* h1s = (ushort*)w; w += alignup((size_t)N * HID * 2);
    ushort* h2s = (ushort*)w; w += alignup((size_t)N * OUTC * 2);
    ushort* WThi = (ushort*)w; w += alignup((size_t)HID * IN_C * 2);
    ushort* WTlo = (ushort*)w; w += alignup((size_t)HID * IN_C * 2);

    const int n4 = (N + 3) / 4;                 // int4 count covering cnt
    k_zero<<<(n4 + 255) / 256, 256, 0, stream>>>((int4*)cnt, n4);

    const int nb   = (N + 255) / 256;
    const int nbE2 = (E / 2 + 255) / 256;
    const int nbW  = (HID * IN_C + 255) / 256;
    k_histsplit<<<nbE2 + nbW, 256, 0, stream>>>(dst, E, cnt, rank, nbE2, W1, WThi, WTlo);
    k_scan1 <<<nb, 256, 0, stream>>>(cnt, N, rowptr, bsum);
    k_scan23<<<nb, 256, 0, stream>>>(rowptr, bsum, cnt, dinv, N, E, nb);
    k_fill  <<<nbE2, 256, 0, stream>>>(src, dst, rank, E, rowptr, ssort);

    k_gemm1 <<<(N + 63) / 64, 256, 0, stream>>>(x, WThi, WTlo, dinv, h1s, N);
    k_agg1g2<<<2048, 256, 0, stream>>>(h1s, rowptr, ssort, dinv, b1, W2, h2s, N);
    k_agg2  <<<(N + 3) / 4, 256, 0, stream>>>(h2s, rowptr, ssort, dinv, b2, (float*)d_out, N);
}

// Round 10
// 142.936 us; speedup vs baseline: 1.0329x; 1.0329x over previous
//
#include <hip/hip_runtime.h>
#include <math.h>

#define IN_C 512
#define HID  64
#define OUTC 40

typedef __attribute__((ext_vector_type(8))) short bf16x8;
typedef __attribute__((ext_vector_type(4))) short bf16x4;
typedef __attribute__((ext_vector_type(4))) float f32x4;

#define GDEPTH 16

__device__ __forceinline__ ushort f2bf(float f) {          // RNE
    uint u = __float_as_uint(f);
    u += 0x7FFFu + ((u >> 16) & 1u);
    return (ushort)(u >> 16);
}
__device__ __forceinline__ float bf2f(ushort s) {
    return __uint_as_float(((uint)s) << 16);
}

// ---------------- zero cnt ----------------
__global__ void k_zero(int4* __restrict__ p, int n4) {
    int i = blockIdx.x * blockDim.x + threadIdx.x;
    if (i < n4) p[i] = make_int4(0, 0, 0, 0);
}

// ---------------- histogram of dst + per-edge rank (+ W1 split folded in) ----------------
__global__ void k_histsplit(const int* __restrict__ dst, int E,
                            int* __restrict__ cnt, int* __restrict__ rank,
                            int nbE2,
                            const float* __restrict__ W,
                            ushort* __restrict__ hi, ushort* __restrict__ lo) {
    if (blockIdx.x < (unsigned)nbE2) {
        int i = (blockIdx.x * blockDim.x + threadIdx.x) * 2;
        if (i < E) {
            if (i + 1 < E) {
                int2 d = *(const int2*)&dst[i];
                int r0 = atomicAdd(&cnt[d.x], 1);
                int r1 = atomicAdd(&cnt[d.y], 1);
                *(int2*)&rank[i] = make_int2(r0, r1);
            } else {
                rank[i] = atomicAdd(&cnt[dst[i]], 1);
            }
        }
    } else {
        // W1 split to hi/lo bf16, transposed: WT[c][k]
        int i = (blockIdx.x - nbE2) * blockDim.x + threadIdx.x;   // over 64*512
        if (i >= HID * IN_C) return;
        int c = i >> 9, k = i & 511;
        float v = W[(size_t)k * HID + c];
        uint ub = __float_as_uint(v);
        uint hb = ub & 0xFFFF0000u;
        float lf = v - __uint_as_float(hb);
        hi[i] = (ushort)(ub >> 16);
        lo[i] = (ushort)(__float_as_uint(lf) >> 16);
    }
}

// ---------------- prefix scan ----------------
__global__ void k_scan1(const int* __restrict__ cnt, int N,
                        int* __restrict__ rowptr, int* __restrict__ bsum) {
    __shared__ int s[256];
    int t = threadIdx.x;
    int i = blockIdx.x * 256 + t;
    int v = (i < N) ? cnt[i] : 0;
    int x = v;
    s[t] = x; __syncthreads();
    #pragma unroll
    for (int o = 1; o < 256; o <<= 1) {
        int y = (t >= o) ? s[t - o] : 0;
        __syncthreads();
        x += y; s[t] = x;
        __syncthreads();
    }
    if (i < N) rowptr[i] = x - v;          // exclusive
    if (t == 255) bsum[blockIdx.x] = x;    // block total
}

// scan2+scan3 fused
__global__ void k_scan23(int* __restrict__ rowptr, const int* __restrict__ bsum,
                         const int* __restrict__ cnt, float* __restrict__ dinv,
                         int N, int E, int nb) {
    __shared__ int s[256];
    int t = threadIdx.x;
    int v = (t < nb) ? bsum[t] : 0;
    int x = v;
    s[t] = x; __syncthreads();
    #pragma unroll
    for (int o = 1; o < 256; o <<= 1) {
        int y = (t >= o) ? s[t - o] : 0;
        __syncthreads();
        x += y; s[t] = x;
        __syncthreads();
    }
    int bpre = (blockIdx.x > 0) ? s[blockIdx.x - 1] : 0;
    int i = blockIdx.x * 256 + t;
    if (i < N) {
        rowptr[i] += bpre;
        dinv[i] = rsqrtf(1.0f + (float)cnt[i]);   // self-loop => deg >= 1
        if (i == 0) rowptr[N] = E;
    }
}

// ---------------- GEMM1 (LDS-staged split-bf16 MFMA) + fill merged ----------------
// Blocks [0, nbG): gemm1, identical structure to the verified round-9 kernel.
// Blocks [nbG, ...): atomic-free counting-sort scatter (independent work,
// overlapped under gemm1's HBM streaming; early-return, no barriers).
__global__ __launch_bounds__(256) void k_gemm1fill(
        const float* __restrict__ x,
        const ushort* __restrict__ WThi, const ushort* __restrict__ WTlo,
        const float* __restrict__ dinv, ushort* __restrict__ h1s,
        int N, int nbG,
        const int* __restrict__ src, const int* __restrict__ dst,
        const int* __restrict__ rank, int E,
        const int* __restrict__ rowptr, int* __restrict__ ssort) {
    __shared__ ushort Ah[2][64 * 40], Al[2][64 * 40];
    __shared__ ushort Bh[2][64 * 40], Bl[2][64 * 40];

    if (blockIdx.x >= (unsigned)nbG) {
        // ---- fill path ----
        int i = ((blockIdx.x - nbG) * blockDim.x + threadIdx.x) * 2;
        if (i >= E) return;
        if (i + 1 < E) {
            int2 d = *(const int2*)&dst[i];
            int2 s = *(const int2*)&src[i];
            int2 r = *(const int2*)&rank[i];
            ssort[rowptr[d.x] + r.x] = s.x;
            ssort[rowptr[d.y] + r.y] = s.y;
        } else {
            ssort[rowptr[dst[i]] + rank[i]] = src[i];
        }
        return;
    }

    // ---- gemm path ----
    int t = threadIdx.x;
    int wid = t >> 6, lane = t & 63;
    int lr = lane & 15, lko = lane >> 4;
    int wm = wid >> 1, wn = wid & 1;
    int row0 = blockIdx.x * 64;

    int srow = t >> 3, sf4 = t & 7;
    int scol = t >> 2, sseg = t & 3;
    int xr0 = row0 + srow;      if (xr0 >= N) xr0 = N - 1;
    int xr1 = row0 + srow + 32; if (xr1 >= N) xr1 = N - 1;
    const float* xp0 = x + (size_t)xr0 * IN_C + sf4 * 4;
    const float* xp1 = x + (size_t)xr1 * IN_C + sf4 * 4;
    const ushort* bhp = WThi + (size_t)scol * IN_C + sseg * 8;
    const ushort* blp = WTlo + (size_t)scol * IN_C + sseg * 8;

    f32x4 acc[2][2] = {};
    float4 xrg[2];
    bf16x8 bhr, blr;

    auto stage_load = [&](int kt) {
        xrg[0] = *(const float4*)(xp0 + kt);
        xrg[1] = *(const float4*)(xp1 + kt);
        bhr = *(const bf16x8*)(bhp + kt);
        blr = *(const bf16x8*)(blp + kt);
    };
    auto stage_write = [&](int b) {
        #pragma unroll
        for (int p = 0; p < 2; ++p) {
            float xv[4];
            *(float4*)xv = xrg[p];
            bf16x4 h, l;
            #pragma unroll
            for (int j = 0; j < 4; ++j) {
                uint ub = __float_as_uint(xv[j]);
                float hf = __uint_as_float(ub & 0xFFFF0000u);
                float lf = xv[j] - hf;
                h[j] = (short)(ub >> 16);
                l[j] = (short)(__float_as_uint(lf) >> 16);
            }
            int row = srow + p * 32;
            *(bf16x4*)&Ah[b][row * 40 + sf4 * 4] = h;
            *(bf16x4*)&Al[b][row * 40 + sf4 * 4] = l;
        }
        *(bf16x8*)&Bh[b][scol * 40 + sseg * 8] = bhr;
        *(bf16x8*)&Bl[b][scol * 40 + sseg * 8] = blr;
    };
    auto compute = [&](int b) {
        bf16x8 afh[2], afl[2], bfh[2], bfl[2];
        #pragma unroll
        for (int mf = 0; mf < 2; ++mf) {
            int row = wm * 32 + mf * 16 + lr;
            afh[mf] = *(const bf16x8*)&Ah[b][row * 40 + lko * 8];
            afl[mf] = *(const bf16x8*)&Al[b][row * 40 + lko * 8];
        }
        #pragma unroll
        for (int nf = 0; nf < 2; ++nf) {
            int col = wn * 32 + nf * 16 + lr;
            bfh[nf] = *(const bf16x8*)&Bh[b][col * 40 + lko * 8];
            bfl[nf] = *(const bf16x8*)&Bl[b][col * 40 + lko * 8];
        }
        #pragma unroll
        for (int mf = 0; mf < 2; ++mf)
            #pragma unroll
            for (int nf = 0; nf < 2; ++nf) {
                acc[mf][nf] = __builtin_amdgcn_mfma_f32_16x16x32_bf16(afh[mf], bfh[nf], acc[mf][nf], 0, 0, 0);
                acc[mf][nf] = __builtin_amdgcn_mfma_f32_16x16x32_bf16(afl[mf], bfh[nf], acc[mf][nf], 0, 0, 0);
                acc[mf][nf] = __builtin_amdgcn_mfma_f32_16x16x32_bf16(afh[mf], bfl[nf], acc[mf][nf], 0, 0, 0);
            }
    };

    stage_load(0);
    stage_write(0);
    __syncthreads();

    #pragma unroll
    for (int i = 0; i < 16; ++i) {
        if (i < 15) stage_load((i + 1) * 32);
        compute(i & 1);
        if (i < 15) stage_write((i + 1) & 1);
        __syncthreads();
    }

    #pragma unroll
    for (int mf = 0; mf < 2; ++mf)
        #pragma unroll
        for (int r = 0; r < 4; ++r) {
            int orow = row0 + wm * 32 + mf * 16 + lko * 4 + r;
            if (orow < N) {
                float dv = dinv[orow];
                #pragma unroll
                for (int nf = 0; nf < 2; ++nf)
                    h1s[(size_t)orow * HID + wn * 32 + nf * 16 + lr] = f2bf(dv * acc[mf][nf][r]);
            }
        }
}

// ---------------- fused agg1 + gemm2 (bf16 h1s gather, bf16 h2s out) ----------------
__global__ __launch_bounds__(256) void k_agg1g2(const ushort* __restrict__ h1s,
                                                const int* __restrict__ rowptr,
                                                const int* __restrict__ ssort,
                                                const float* __restrict__ dinv,
                                                const float* __restrict__ b1,
                                                const float* __restrict__ W2,
                                                ushort* __restrict__ h2s, int N) {
    __shared__ float wl[HID * OUTC];      // 2560 floats = 10.24 KB
    int t = threadIdx.x;
    #pragma unroll
    for (int q0 = 0; q0 < 3; ++q0) {
        int q = t + q0 * 256;
        if (q < 640) *(float4*)&wl[q * 4] = *(const float4*)&W2[q * 4];
    }
    __syncthreads();

    int lane = t & 63;
    int wq = t >> 6;
    int lc = lane < OUTC ? lane : 0;
    float bias = b1[lane];
    int nq = (N + 3) >> 2;

    for (int q = blockIdx.x; q < nq; q += gridDim.x) {
        int node = q * 4 + wq;
        if (node >= N) continue;
        float s0 = bf2f(h1s[(size_t)node * HID + lane]);   // self-loop term
        float sv[GDEPTH];
        #pragma unroll
        for (int k = 0; k < GDEPTH; ++k) sv[k] = 0.f;
        int eu = __builtin_amdgcn_readfirstlane(rowptr[node]);
        int endu = __builtin_amdgcn_readfirstlane(rowptr[node + 1]);
        for (int e = eu; e < endu; e += GDEPTH) {
            int raw[GDEPTH];
            #pragma unroll
            for (int k = 0; k < GDEPTH; ++k) raw[k] = ssort[e + k];  // scalar s_load path
            #pragma unroll
            for (int k = 0; k < GDEPTH; ++k) {
                int ix = (e + k < endu) ? raw[k] : raw[0];
                float v = bf2f(h1s[(size_t)ix * HID + lane]);
                sv[k] += (e + k < endu) ? v : 0.f;
            }
        }
        float s = s0;
        #pragma unroll
        for (int k = 0; k < GDEPTH; ++k) s += sv[k];
        float dv = dinv[node];
        float a = fmaxf(fmaf(dv, s, bias), 0.0f);
        // in-wave gemm2: h2[c] = sum_k a[k] * W2[k][c]
        float acc = 0.f;
        #pragma unroll
        for (int k = 0; k < HID; ++k) {
            float ak = __uint_as_float(__builtin_amdgcn_readlane(__float_as_uint(a), k));
            acc = fmaf(ak, wl[k * OUTC + lc], acc);
        }
        if (lane < OUTC) h2s[(size_t)node * OUTC + lane] = f2bf(dv * acc);
    }
}

// ---------------- agg2 + bias + softmax (bf16 h2s gather) ----------------
__global__ __launch_bounds__(256) void k_agg2(const ushort* __restrict__ h2s,
                                              const int* __restrict__ rowptr,
                                              const int* __restrict__ ssort,
                                              const float* __restrict__ dinv,
                                              const float* __restrict__ b2,
                                              float* __restrict__ out, int N) {
    int lane = threadIdx.x & 63;
    int node = blockIdx.x * 4 + (threadIdx.x >> 6);
    if (node >= N) return;
    bool act = lane < OUTC;
    int lc = act ? lane : 0;
    float s0 = bf2f(h2s[(size_t)node * OUTC + lc]);
    float sv[GDEPTH];
    #pragma unroll
    for (int k = 0; k < GDEPTH; ++k) sv[k] = 0.f;
    int eu = __builtin_amdgcn_readfirstlane(rowptr[node]);
    int endu = __builtin_amdgcn_readfirstlane(rowptr[node + 1]);
    for (int e = eu; e < endu; e += GDEPTH) {
        int raw[GDEPTH];
        #pragma unroll
        for (int k = 0; k < GDEPTH; ++k) raw[k] = ssort[e + k];
        #pragma unroll
        for (int k = 0; k < GDEPTH; ++k) {
            int ix = (e + k < endu) ? raw[k] : raw[0];
            float v = bf2f(h2s[(size_t)ix * OUTC + lc]);
            sv[k] += (e + k < endu) ? v : 0.f;
        }
    }
    float s = s0;
    #pragma unroll
    for (int k = 0; k < GDEPTH; ++k) s += sv[k];
    float v = act ? (dinv[node] * s + b2[lane]) : -INFINITY;
    float m = v;
    #pragma unroll
    for (int o = 32; o; o >>= 1) m = fmaxf(m, __shfl_xor(m, o));
    float p = act ? expf(v - m) : 0.0f;
    float su = p;
    #pragma unroll
    for (int o = 32; o; o >>= 1) su += __shfl_xor(su, o);
    if (act) out[(size_t)node * OUTC + lane] = p / su;
}

static inline size_t alignup(size_t v) { return (v + 255) & ~(size_t)255; }

extern "C" void kernel_launch(void* const* d_in, const int* in_sizes, int n_in,
                              void* d_out, int out_size, void* d_ws, size_t ws_size,
                              hipStream_t stream) {
    const float* x  = (const float*)d_in[0];
    const int*   ei = (const int*)d_in[1];
    const float* W1 = (const float*)d_in[2];
    const float* b1 = (const float*)d_in[3];
    const float* W2 = (const float*)d_in[4];
    const float* b2 = (const float*)d_in[5];

    const int N = in_sizes[0] / IN_C;
    const int E = in_sizes[1] / 2;
    const int* src = ei;
    const int* dst = ei + E;

    char* w = (char*)d_ws;
    int* cnt    = (int*)w;   w += alignup((size_t)N * 4);
    int* rank   = (int*)w;   w += alignup((size_t)E * 4 + 256);
    int* rowptr = (int*)w;   w += alignup((size_t)(N + 1) * 4);
    int* bsum   = (int*)w;   w += alignup(256 * 4);
    int* ssort  = (int*)w;   w += alignup((size_t)E * 4 + 256);  // +pad: scalar tail overreads
    float* dinv = (float*)w; w += alignup((size_t)N * 4);
    ushort* h1s = (ushort*)w; w += alignup((size_t)N * HID * 2);
    ushort* h2s = (ushort*)w; w += alignup((size_t)N * OUTC * 2);
    ushort* WThi = (ushort*)w; w += alignup((size_t)HID * IN_C * 2);
    ushort* WTlo = (ushort*)w; w += alignup((size_t)HID * IN_C * 2);

    const int n4 = (N + 3) / 4;                 // int4 count covering cnt
    k_zero<<<(n4 + 255) / 256, 256, 0, stream>>>((int4*)cnt, n4);

    const int nb   = (N + 255) / 256;
    const int nbE2 = (E / 2 + 255) / 256;
    const int nbW  = (HID * IN_C + 255) / 256;
    k_histsplit<<<nbE2 + nbW, 256, 0, stream>>>(dst, E, cnt, rank, nbE2, W1, WThi, WTlo);
    k_scan1 <<<nb, 256, 0, stream>>>(cnt, N, rowptr, bsum);
    k_scan23<<<nb, 256, 0, stream>>>(rowptr, bsum, cnt, dinv, N, E, nb);

    const int nbG = (N + 63) / 64;
    k_gemm1fill<<<nbG + nbE2, 256, 0, stream>>>(x, WThi, WTlo, dinv, h1s, N, nbG,
                                                src, dst, rank, E, rowptr, ssort);
    k_agg1g2<<<2048, 256, 0, stream>>>(h1s, rowptr, ssort, dinv, b1, W2, h2s, N);
    k_agg2  <<<(N + 3) / 4, 256, 0, stream>>>(h2s, rowptr, ssort, dinv, b2, (float*)d_out, N);
}